// Round 4
// baseline (350.898 us; speedup 1.0000x reference)
//
#include <hip/hip_runtime.h>
#include <hip/hip_bf16.h>
#include <hip/hip_fp16.h>
#include <type_traits>

// ---- problem constants ----
#define B_    2
#define LQ_   21760
#define LEN_  21760
#define DM    256
#define NH    8
#define NL    4
#define NP    4
#define HD    32

// workspace layout (bytes)
#define WS_VAL   0u            // f16 value [B][H][21760][32]      22,282,240
#define WS_SAMP  22282240u     // bf16 sampled [B*LQ][256]         22,282,240
#define WS_WT    44564480u     // bf16 W^T arena: val|oa|out        458,752

typedef __attribute__((ext_vector_type(4))) float f32x4;
typedef __attribute__((ext_vector_type(8))) short bf16x8;
typedef __attribute__((ext_vector_type(4))) unsigned int u32x4;
typedef __attribute__((ext_vector_type(2))) unsigned int u32x2;

__device__ __forceinline__ unsigned short f2bf(float v) {
    __hip_bfloat16 h = __float2bfloat16(v);
    return *reinterpret_cast<unsigned short*>(&h);
}
__device__ __forceinline__ unsigned int pk2bf(float a, float b) {
    return (unsigned int)f2bf(a) | ((unsigned int)f2bf(b) << 16);
}
__device__ __forceinline__ unsigned int pk2h(float a, float b) {
    __half2 h = __floats2half2_rn(a, b);
    union { __half2 h; unsigned int u; } c; c.h = h; return c.u;
}
__device__ __forceinline__ __half2 u2h2(unsigned int u) {
    union { unsigned int u; __half2 h; } c; c.u = u; return c.h;
}

// forced 16-B gather: named register quad, cannot be re-rolled by the scheduler
__device__ __forceinline__ void gload16(u32x4& d, const char* p) {
    asm volatile("global_load_dwordx4 %0, %1, off" : "=v"(d) : "v"(p));
}

// ---------------------------------------------------------------------------
// All four weight transposes in one dispatch. W[K=256,N] f32 -> Wt[N,256] bf16.
// ---------------------------------------------------------------------------
__global__ __launch_bounds__(256) void wt_cvt_all(const float* __restrict__ Wv,
                                                  const float* __restrict__ Wo,
                                                  const float* __restrict__ Wa,
                                                  const float* __restrict__ Wu,
                                                  unsigned short* __restrict__ wt) {
    const float* Ws[4] = {Wv, Wo, Wa, Wu};
    const int Ns[4] = {256, 256, 128, 256};
    const unsigned int dof[4] = {0u, 65536u, 131072u, 163840u};
    const int m = blockIdx.z;
    const int n0 = blockIdx.x * 16, k0 = blockIdx.y * 16;
    if (n0 >= Ns[m]) return;
    __shared__ float tile[16][17];
    const int tx = threadIdx.x & 15, ty = threadIdx.x >> 4;
    tile[ty][tx] = Ws[m][(size_t)(k0 + ty) * Ns[m] + n0 + tx];
    __syncthreads();
    wt[dof[m] + (size_t)(n0 + ty) * 256 + k0 + tx] = f2bf(tile[tx][ty]);
}

// ---------------------------------------------------------------------------
// value = inpf @ Wt_val + b_val -> f16, PERMUTED [b][h][pix][32].
// 128x128 tile, BK=32, 4 waves. grid (2, 340).
// (oa GEMM moved into msda_sample9 -- each block needs only a 32x48 slice.)
// ---------------------------------------------------------------------------
__global__ __launch_bounds__(256) void gemm_val(const float* __restrict__ inpf,
                                                const unsigned short* __restrict__ Wt_val,
                                                const float* __restrict__ b_val,
                                                unsigned short* __restrict__ val_h) {
    __shared__ unsigned short As[128 * 32];
    __shared__ unsigned short Bs[128 * 32];
    const int t = threadIdx.x;
    const int wv = t >> 6;
    const int ln = t & 63;
    const int n0 = blockIdx.x * 128;
    const int m0 = blockIdx.y * 128;
    const int K = 256;
    const int wm = (wv & 1) * 64;
    const int wn = (wv >> 1) * 64;
    const int lrow = ln & 15;
    const int kq = ln >> 4;

    f32x4 acc[4][4] = {};

    for (int k0 = 0; k0 < K; k0 += 32) {
#pragma unroll
        for (int c = 0; c < 4; ++c) {
            const int i = t + c * 256;
            const int row = i >> 3;
            const int kq4 = (i & 7) * 4;
            f32x4 v = *(const f32x4*)&inpf[(size_t)(m0 + row) * K + k0 + kq4];
            uint2 p = make_uint2(pk2bf(v.x, v.y), pk2bf(v.z, v.w));
            *(uint2*)((char*)As + row * 64 + kq4 * 2) = p;
        }
#pragma unroll
        for (int c = 0; c < 2; ++c) {
            const int o = c * 4096 + t * 16;
            const int row = o >> 6;
            const int ke = (o & 63) >> 1;
            const unsigned short* gb = Wt_val + (size_t)(n0 + row) * K + k0 + ke;
            __builtin_amdgcn_global_load_lds(
                (const __attribute__((address_space(1))) void*)gb,
                (__attribute__((address_space(3))) void*)((char*)Bs + o), 16, 0, 0);
        }
        __syncthreads();

        bf16x8 af[4], bfr[4];
#pragma unroll
        for (int i = 0; i < 4; ++i) {
            af[i]  = *(const bf16x8*)((char*)As + (wm + i * 16 + lrow) * 64 + kq * 16);
            bfr[i] = *(const bf16x8*)((char*)Bs + (wn + i * 16 + lrow) * 64 + kq * 16);
        }
#pragma unroll
        for (int i = 0; i < 4; ++i)
#pragma unroll
            for (int j = 0; j < 4; ++j)
                acc[i][j] = __builtin_amdgcn_mfma_f32_16x16x32_bf16(af[i], bfr[j], acc[i][j], 0, 0, 0);
        __syncthreads();
    }

    // epilogue: C/D mapping col = lane&15, row = (lane>>4)*4 + reg
    const int b = m0 / LQ_;       // block never straddles batch (21760 % 128 == 0)
#pragma unroll
    for (int j = 0; j < 4; ++j) {
        const int n = n0 + wn + j * 16 + lrow;
        const float bb = b_val[n];
#pragma unroll
        for (int i = 0; i < 4; ++i) {
            const int mrow = m0 + wm + i * 16 + kq * 4;
#pragma unroll
            for (int r = 0; r < 4; ++r) {
                const float v = acc[i][j][r] + bb;
                const unsigned short hv = (unsigned short)__half_as_ushort(__float2half(v));
                const int pix = (mrow + r) - b * LQ_;
                const int hh = n >> 5, c = n & 31;
                val_h[((size_t)(b * NH + hh) * LQ_ + pix) * HD + c] = hv;
            }
        }
    }
}

// ---------------------------------------------------------------------------
// out = sampled(bf16) @ Wt_out + b_out -> f32. grid (2, 340).
// ---------------------------------------------------------------------------
__global__ __launch_bounds__(256) void gemm_out(const unsigned short* __restrict__ Ab,
                                                const unsigned short* __restrict__ Bt,
                                                const float* __restrict__ bias,
                                                float* __restrict__ C) {
    __shared__ unsigned short As[128 * 32];
    __shared__ unsigned short Bs[128 * 32];
    const int t = threadIdx.x;
    const int wv = t >> 6;
    const int ln = t & 63;
    const int n0 = blockIdx.x * 128;
    const int m0 = blockIdx.y * 128;
    const int N = 256, K = 256;
    const int wm = (wv & 1) * 64;
    const int wn = (wv >> 1) * 64;
    const int lrow = ln & 15;
    const int kq = ln >> 4;

    f32x4 acc[4][4] = {};

    for (int k0 = 0; k0 < K; k0 += 32) {
#pragma unroll
        for (int c = 0; c < 2; ++c) {
            const int o = c * 4096 + t * 16;
            const int row = o >> 6;
            const int ke = (o & 63) >> 1;
            const unsigned short* ga = Ab + (size_t)(m0 + row) * K + k0 + ke;
            const unsigned short* gb = Bt + (size_t)(n0 + row) * K + k0 + ke;
            __builtin_amdgcn_global_load_lds(
                (const __attribute__((address_space(1))) void*)ga,
                (__attribute__((address_space(3))) void*)((char*)As + o), 16, 0, 0);
            __builtin_amdgcn_global_load_lds(
                (const __attribute__((address_space(1))) void*)gb,
                (__attribute__((address_space(3))) void*)((char*)Bs + o), 16, 0, 0);
        }
        __syncthreads();

        bf16x8 af[4], bfr[4];
#pragma unroll
        for (int i = 0; i < 4; ++i) {
            af[i]  = *(const bf16x8*)((char*)As + (wm + i * 16 + lrow) * 64 + kq * 16);
            bfr[i] = *(const bf16x8*)((char*)Bs + (wn + i * 16 + lrow) * 64 + kq * 16);
        }
#pragma unroll
        for (int i = 0; i < 4; ++i)
#pragma unroll
            for (int j = 0; j < 4; ++j)
                acc[i][j] = __builtin_amdgcn_mfma_f32_16x16x32_bf16(af[i], bfr[j], acc[i][j], 0, 0, 0);
        __syncthreads();
    }

#pragma unroll
    for (int j = 0; j < 4; ++j) {
        const int n = n0 + wn + j * 16 + lrow;
        const float bb = bias[n];
#pragma unroll
        for (int i = 0; i < 4; ++i) {
            const int mrow = m0 + wm + i * 16 + kq * 4;
#pragma unroll
            for (int r = 0; r < 4; ++r)
                C[(size_t)(mrow + r) * N + n] = acc[i][j][r] + bb;
        }
    }
}

// ---------------------------------------------------------------------------
// Deformable sampling v9 = v8 phase-B (ISA-forced pipeline, at the request
// wall) + FUSED oa micro-GEMM. Each block (head h, 32 queries) computes its
// own 32x48 slice of (query @ W_oa + b): 12 MFMA/wave hidden under the
// gather wall, killing the 33 MB oa intermediate (write+read) and 60% of
// the pre-GEMM dispatch.
//   micro-GEMM: 4 waves = (m-tile 0/1) x (k-half 0/1); partials reduced
//   via LDS. A = query staged f32->bf16 in LDS, XOR-swizzled (G4);
//   B = Wt_oa rows read direct from global (24 kB slice, L1-resident per CU
//   since same-h blocks recur on the same XCD).
// ---------------------------------------------------------------------------
#define QB6 32

#define MSDA_VMWAIT(n) { asm volatile("s_waitcnt vmcnt(" #n ")" ::: "memory"); \
                         __builtin_amdgcn_sched_barrier(0); }

#define MSDA_ISSUE(i) u32x4 va_##i, vc_##i; { \
    const u32x2 xy = *(const u32x2*)&s_pkw[wb ^ ((i) << 2)]; \
    gload16(va_##i, vbase + (size_t)xy[0] * 64); \
    gload16(vc_##i, vbase + (size_t)xy[1] * 64); }

#define MSDA_CONSUME(i) { \
    const u32x2 zw = *(const u32x2*)&s_pkw[(wb ^ ((i) << 2)) + 2]; \
    const __half2 w0 = u2h2(__builtin_amdgcn_perm(zw[0], zw[0], wsel)); \
    const __half2 w1 = u2h2(__builtin_amdgcn_perm(zw[1], zw[1], wsel)); \
    ah0 = __hfma2(w0, u2h2(va_##i[0]), ah0); \
    ah1 = __hfma2(w0, u2h2(va_##i[1]), ah1); \
    ah2 = __hfma2(w0, u2h2(va_##i[2]), ah2); \
    ah3 = __hfma2(w0, u2h2(va_##i[3]), ah3); \
    ah0 = __hfma2(w1, u2h2(vc_##i[0]), ah0); \
    ah1 = __hfma2(w1, u2h2(vc_##i[1]), ah1); \
    ah2 = __hfma2(w1, u2h2(vc_##i[2]), ah2); \
    ah3 = __hfma2(w1, u2h2(vc_##i[3]), ah3); }

#define MSDA_FLUSH() { \
    float2 f0 = __half22float2(ah0); facc0 += f0.x; facc1 += f0.y; ah0 = u2h2(0u); \
    float2 f1 = __half22float2(ah1); facc2 += f1.x; facc3 += f1.y; ah1 = u2h2(0u); \
    float2 f2 = __half22float2(ah2); facc4 += f2.x; facc5 += f2.y; ah2 = u2h2(0u); \
    float2 f3 = __half22float2(ah3); facc6 += f3.x; facc7 += f3.y; ah3 = u2h2(0u); }

__global__ __launch_bounds__(256) void msda_sample9(const unsigned short* __restrict__ value,
                                                    const unsigned short* __restrict__ wt_oa,
                                                    const float* __restrict__ b_off,
                                                    const float* __restrict__ b_attn,
                                                    const float* __restrict__ query,
                                                    const float* __restrict__ refp,
                                                    unsigned short* __restrict__ samp) {
    __shared__ __align__(16) char smem[25600];
    // region 0 [0,16384): s_qt bf16 [32][256] swizzled; later aliased by
    //                     s_part f32 [2][32][48] (12 kB)  (qt dead by then)
    unsigned short* s_qt = (unsigned short*)smem;
    float* s_part = (float*)smem;
    // region 1 [16384,24576): s_off|s_logit|s_aw, aliased by s_pkw in phase B
    float* s_off   = (float*)(smem + 16384);              // 32q*32 f32 = 4 KB
    float* s_logit = (float*)(smem + 20480);              // 32q*16 f32 = 2 KB
    float* s_aw    = (float*)(smem + 22528);              // 2 KB
    unsigned int* s_pkw = (unsigned int*)(smem + 16384);  // 8 KB (phase B)
    float* s_ref   = (float*)(smem + 24576);              // 1 KB (non-aliased)

    const int t = threadIdx.x;
    const int j = blockIdx.x;                 // 10880 blocks
    const int h = j & 7;                      // head, pinned per XCD
    const int bqc = j >> 3;                   // 0..1359
    const int b = (bqc >= 680);
    const int q0 = (bqc - b * 680) * QB6;     // batch-local query base
    const int bq0 = b * LQ_ + q0;             // global row base
    const int lane = t & 63;
    const int wv = t >> 6;

    // phase -1: stage query rows (f32 -> bf16, XOR-swizzled) + refs
    {
        const int q = t >> 3, c = t & 7;      // 8 threads/row, 32 f32 each
        const float* qrow = query + (size_t)(bq0 + q) * 256 + c * 32;
        const int rb = q * 512;
        const int sw = (q & 7) << 4;
#pragma unroll
        for (int v = 0; v < 4; ++v) {
            f32x4 x0 = *(const f32x4*)(qrow + v * 8);
            f32x4 x1 = *(const f32x4*)(qrow + v * 8 + 4);
            u32x4 p;
            p.x = pk2bf(x0.x, x0.y); p.y = pk2bf(x0.z, x0.w);
            p.z = pk2bf(x1.x, x1.y); p.w = pk2bf(x1.z, x1.w);
            *(u32x4*)((char*)s_qt + rb + ((c * 64 + v * 16) ^ sw)) = p;
        }
        s_ref[q * 8 + c] = __builtin_nontemporal_load(refp + (size_t)(bq0 + q) * 8 + c);
    }
    __syncthreads();

    // micro-GEMM: oa[32q][48n] = query[32][256] @ Wt_oa_slice; K split over waves
    {
        const int mt = wv & 1;                // m-tile (16 q-rows)
        const int kh = wv >> 1;               // k-half (128)
        const int lr = lane & 15, kq = lane >> 4;
        const int arow = mt * 16 + lr;
        const int abase = arow * 512;
        const int asw = (arow & 7) << 4;
        const unsigned short* bt0 = wt_oa + ((size_t)(h * 32) + lr) * 256;
        const unsigned short* bt1 = wt_oa + ((size_t)(h * 32 + 16) + lr) * 256;
        const unsigned short* bt2 = wt_oa + ((size_t)(256 + h * 16) + lr) * 256;
        f32x4 acc0 = {0.f, 0.f, 0.f, 0.f}, acc1 = acc0, acc2 = acc0;
#pragma unroll
        for (int s = 0; s < 4; ++s) {
            const int k = kh * 128 + s * 32 + kq * 8;   // bf16 element index
            bf16x8 af  = *(const bf16x8*)((char*)s_qt + abase + ((k * 2) ^ asw));
            bf16x8 bf0 = *(const bf16x8*)(bt0 + k);
            bf16x8 bf1 = *(const bf16x8*)(bt1 + k);
            bf16x8 bf2 = *(const bf16x8*)(bt2 + k);
            acc0 = __builtin_amdgcn_mfma_f32_16x16x32_bf16(af, bf0, acc0, 0, 0, 0);
            acc1 = __builtin_amdgcn_mfma_f32_16x16x32_bf16(af, bf1, acc1, 0, 0, 0);
            acc2 = __builtin_amdgcn_mfma_f32_16x16x32_bf16(af, bf2, acc2, 0, 0, 0);
        }
        __syncthreads();   // all qt reads done -> safe to alias with s_part
        // partials: part[kh][q][n]; q = mt*16 + kq*4 + r, n = nt*16 + lr
        float* pb = s_part + kh * 1536;
#pragma unroll
        for (int r = 0; r < 4; ++r) {
            const int q = mt * 16 + kq * 4 + r;
            pb[q * 48 + lr]      = acc0[r];
            pb[q * 48 + 16 + lr] = acc1[r];
            pb[q * 48 + 32 + lr] = acc2[r];
        }
    }
    __syncthreads();

    // finalize: sum k-halves + bias -> s_off / s_logit
#pragma unroll
    for (int e = 0; e < 6; ++e) {
        const int idx = t + e * 256;          // 0..1535
        const int q = (idx * 1366) >> 16;     // idx / 48
        const int n = idx - q * 48;
        const float v = s_part[q * 48 + n] + s_part[1536 + q * 48 + n]
                      + ((n < 32) ? b_off[h * 32 + n] : b_attn[h * 16 + n - 32]);
        if (n < 32) s_off[q * 32 + n] = v;
        else        s_logit[q * 16 + n - 32] = v;
    }
    __syncthreads();

    // phase A1: 32 softmaxes (one per query, this head) over 16 logits
    if (t < 32) {
        const float* lg = s_logit + t * 16;
        float m = -1e30f;
#pragma unroll
        for (int i = 0; i < 16; ++i) m = fmaxf(m, lg[i]);
        float e[16], s = 0.f;
#pragma unroll
        for (int i = 0; i < 16; ++i) { e[i] = __expf(lg[i] - m); s += e[i]; }
        const float inv = 1.f / s;
#pragma unroll
        for (int i = 0; i < 16; ++i) s_aw[t * 16 + i] = e[i] * inv;
    }
    __syncthreads();

    // phase A2: 2 samples/thread -> registers. s = q(5b)*16 + lp(4b)
    uint4 ent[2];
    int wrd[2];
    {
        const int Wls[4] = {128, 64, 32, 16};
        const int Hls[4] = {128, 64, 32, 16};
        const int st_[4] = {0, 16384, 20480, 21504};
#pragma unroll
        for (int ii = 0; ii < 2; ++ii) {
            const int s = t * 2 + ii;
            const int q = s >> 4;
            const int lp = s & 15;
            const int l = lp >> 2;
            const int Wl = Wls[l], Hl = Hls[l], base = st_[l];
            const float ix = s_ref[q * 8 + l * 2]     * (float)Wl - 0.5f + s_off[q * 32 + lp * 2];
            const float iy = s_ref[q * 8 + l * 2 + 1] * (float)Hl - 0.5f + s_off[q * 32 + lp * 2 + 1];
            const float fix = floorf(ix), fiy = floorf(iy);
            const int x0 = (int)fix, y0 = (int)fiy;
            const float fx = ix - fix, fy = iy - fiy;
            int sx; float wl, wr;
            if (x0 < 0)            { sx = 0;      wl = (x0 == -1) ? fx : 0.f;        wr = 0.f; }
            else if (x0 >= Wl - 1) { sx = Wl - 2; wl = 0.f; wr = (x0 == Wl - 1) ? (1.f - fx) : 0.f; }
            else                   { sx = x0;     wl = 1.f - fx;                     wr = fx; }
            const float g0 = ((y0 >= 0) & (y0 < Hl)) ? (1.f - fy) : 0.f;
            const float g1 = ((y0 + 1 >= 0) & (y0 + 1 < Hl)) ? fy : 0.f;
            const int cy0 = min(max(y0, 0), Hl - 1);
            const int cy1 = min(max(y0 + 1, 0), Hl - 1);
            const float aw = s_aw[q * 16 + lp];
            ent[ii].x = (unsigned int)(base + cy0 * Wl + sx);
            ent[ii].y = (unsigned int)(base + cy1 * Wl + sx);
            ent[ii].z = pk2h(aw * wl * g0, aw * wr * g0);
            ent[ii].w = pk2h(aw * wl * g1, aw * wr * g1);
            wrd[ii] = q * 64 + ((lp ^ (q & 7)) << 2);
        }
    }
    __syncthreads();  // phase-A reads done; safe to overwrite aliased region

#pragma unroll
    for (int ii = 0; ii < 2; ++ii)
        *(uint4*)&s_pkw[wrd[ii]] = ent[ii];
    __syncthreads();

    // phase B: wave = 8 queries x 8 dg; lane's pixel = sx + (dg>=4), ch = (dg&3)*8..
    const int ql = lane >> 3;                 // 0..7 within wave
    const int q = wv * 8 + ql;                // block-local query 0..31
    const int dg = lane & 7;
    const char* vbase = (const char*)(value + ((size_t)(b * NH + h) * LQ_) * HD) + dg * 16;
    const unsigned int wsel = (dg < 4) ? 0x01000100u : 0x03020302u;  // v_perm: replicate lo/hi half
    const int wb = q * 64 + (ql << 2);        // swizzled entry base (bits disjoint from lp<<2)

    float facc0 = 0.f, facc1 = 0.f, facc2 = 0.f, facc3 = 0.f;
    float facc4 = 0.f, facc5 = 0.f, facc6 = 0.f, facc7 = 0.f;
    __half2 ah0 = u2h2(0u), ah1 = u2h2(0u), ah2 = u2h2(0u), ah3 = u2h2(0u);

    // --- forced pipeline: 16 loads in flight steady-state ---
    MSDA_ISSUE(0)  MSDA_ISSUE(1)  MSDA_ISSUE(2)  MSDA_ISSUE(3)
    MSDA_ISSUE(4)  MSDA_ISSUE(5)  MSDA_ISSUE(6)  MSDA_ISSUE(7)
    MSDA_VMWAIT(8)                    // lp 0..3 complete; 4..7 outstanding
    MSDA_ISSUE(8)  MSDA_ISSUE(9)  MSDA_ISSUE(10) MSDA_ISSUE(11)
    MSDA_CONSUME(0) MSDA_CONSUME(1) MSDA_CONSUME(2) MSDA_CONSUME(3)
    MSDA_FLUSH()
    MSDA_VMWAIT(8)                    // lp 4..7 complete; 8..11 outstanding
    MSDA_ISSUE(12) MSDA_ISSUE(13) MSDA_ISSUE(14) MSDA_ISSUE(15)
    MSDA_CONSUME(4) MSDA_CONSUME(5) MSDA_CONSUME(6) MSDA_CONSUME(7)
    MSDA_FLUSH()
    MSDA_VMWAIT(8)                    // lp 8..11 complete; 12..15 outstanding
    MSDA_CONSUME(8) MSDA_CONSUME(9) MSDA_CONSUME(10) MSDA_CONSUME(11)
    MSDA_FLUSH()
    MSDA_VMWAIT(0)                    // all done
    MSDA_CONSUME(12) MSDA_CONSUME(13) MSDA_CONSUME(14) MSDA_CONSUME(15)
    MSDA_FLUSH()

    // combine left-pixel (dg<4) and right-pixel (dg>=4) partials
    facc0 += __shfl_xor(facc0, 4);
    facc1 += __shfl_xor(facc1, 4);
    facc2 += __shfl_xor(facc2, 4);
    facc3 += __shfl_xor(facc3, 4);
    facc4 += __shfl_xor(facc4, 4);
    facc5 += __shfl_xor(facc5, 4);
    facc6 += __shfl_xor(facc6, 4);
    facc7 += __shfl_xor(facc7, 4);

    if (dg < 4) {
        u32x4 o;
        o.x = pk2bf(facc0, facc1);
        o.y = pk2bf(facc2, facc3);
        o.z = pk2bf(facc4, facc5);
        o.w = pk2bf(facc6, facc7);
        __builtin_nontemporal_store(o, (u32x4*)(samp + (size_t)(bq0 + q) * 256 + h * HD + dg * 8));
    }
}

extern "C" void kernel_launch(void* const* d_in, const int* in_sizes, int n_in,
                              void* d_out, int out_size, void* d_ws, size_t ws_size,
                              hipStream_t stream) {
    const float* query  = (const float*)d_in[0];
    const float* refp   = (const float*)d_in[1];
    const float* inpf   = (const float*)d_in[2];
    const float* W_off  = (const float*)d_in[3];
    const float* b_off  = (const float*)d_in[4];
    const float* W_attn = (const float*)d_in[5];
    const float* b_attn = (const float*)d_in[6];
    const float* W_val  = (const float*)d_in[7];
    const float* b_val  = (const float*)d_in[8];
    const float* W_out  = (const float*)d_in[9];
    const float* b_out  = (const float*)d_in[10];
    float* out = (float*)d_out;

    char* ws = (char*)d_ws;
    unsigned short* val_h   = (unsigned short*)(ws + WS_VAL);
    unsigned short* samp_bf = (unsigned short*)(ws + WS_SAMP);
    unsigned short* wt      = (unsigned short*)(ws + WS_WT);
    unsigned short* Wt_val  = wt;
    unsigned short* Wt_oa   = wt + 65536;
    unsigned short* Wt_out  = wt + 163840;

    const int M = B_ * LQ_;          // 43520

    wt_cvt_all<<<dim3(16, 16, 4), 256, 0, stream>>>(W_val, W_off, W_attn, W_out, wt);

    // value GEMM only (oa fused into sampling)
    gemm_val<<<dim3(2, M / 128), 256, 0, stream>>>(inpf, Wt_val, b_val, val_h);

    // sampling + fused oa micro-GEMM (head-partitioned, forced gather pipeline)
    msda_sample9<<<dim3(B_ * NH * (LQ_ / QB6)), 256, 0, stream>>>(
        val_h, Wt_oa, b_off, b_attn, query, refp, samp_bf);

    // output projection
    gemm_out<<<dim3(2, M / 128), 256, 0, stream>>>(samp_bf, Wt_out, b_out, out);
}

// Round 5
// 283.804 us; speedup vs baseline: 1.2364x; 1.2364x over previous
//
#include <hip/hip_runtime.h>
#include <hip/hip_bf16.h>
#include <hip/hip_fp16.h>
#include <type_traits>

// ---- problem constants ----
#define B_    2
#define LQ_   21760
#define LEN_  21760
#define DM    256
#define NH    8
#define NL    4
#define NP    4
#define HD    32

// workspace layout (bytes)
#define WS_VAL   0u            // f16 value [B][H][21760][32]      22,282,240
#define WS_SAMP  22282240u     // bf16 sampled [B*LQ][256]         22,282,240
#define WS_OA    44564480u     // f16 off|attn [B*LQ][384]         33,423,360
#define WS_WT    77987840u     // bf16 W^T arena: val|oa|out        458,752

typedef __attribute__((ext_vector_type(4))) float f32x4;
typedef __attribute__((ext_vector_type(8))) short bf16x8;
typedef __attribute__((ext_vector_type(4))) unsigned int u32x4;
typedef __attribute__((ext_vector_type(2))) unsigned int u32x2;

__device__ __forceinline__ unsigned short f2bf(float v) {
    __hip_bfloat16 h = __float2bfloat16(v);
    return *reinterpret_cast<unsigned short*>(&h);
}
__device__ __forceinline__ unsigned int pk2bf(float a, float b) {
    return (unsigned int)f2bf(a) | ((unsigned int)f2bf(b) << 16);
}
__device__ __forceinline__ unsigned int pk2h(float a, float b) {
    __half2 h = __floats2half2_rn(a, b);
    union { __half2 h; unsigned int u; } c; c.h = h; return c.u;
}
__device__ __forceinline__ __half2 u2h2(unsigned int u) {
    union { unsigned int u; __half2 h; } c; c.u = u; return c.h;
}

// forced 16-B gather: named register quad, cannot be re-rolled by the scheduler
__device__ __forceinline__ void gload16(u32x4& d, const char* p) {
    asm volatile("global_load_dwordx4 %0, %1, off" : "=v"(d) : "v"(p));
}

// ---------------------------------------------------------------------------
// All four weight transposes in one dispatch. W[K=256,N] f32 -> Wt[N,256] bf16.
// ---------------------------------------------------------------------------
__global__ __launch_bounds__(256) void wt_cvt_all(const float* __restrict__ Wv,
                                                  const float* __restrict__ Wo,
                                                  const float* __restrict__ Wa,
                                                  const float* __restrict__ Wu,
                                                  unsigned short* __restrict__ wt) {
    const float* Ws[4] = {Wv, Wo, Wa, Wu};
    const int Ns[4] = {256, 256, 128, 256};
    const unsigned int dof[4] = {0u, 65536u, 131072u, 163840u};
    const int m = blockIdx.z;
    const int n0 = blockIdx.x * 16, k0 = blockIdx.y * 16;
    if (n0 >= Ns[m]) return;
    __shared__ float tile[16][17];
    const int tx = threadIdx.x & 15, ty = threadIdx.x >> 4;
    tile[ty][tx] = Ws[m][(size_t)(k0 + ty) * Ns[m] + n0 + tx];
    __syncthreads();
    wt[dof[m] + (size_t)(n0 + ty) * 256 + k0 + tx] = f2bf(tile[tx][ty]);
}

// ---------------------------------------------------------------------------
// Merged pre-GEMMs (one dispatch, 2 jobs):
//  job0 (x=0..1): value = inpf @ Wt_val + b_val -> f16, PERMUTED [b][h][pix][32]
//  job1 (x=2..4): oa    = query @ Wt_oa + (b_off|b_attn) -> f16 flat [bq][384]
// 128x128 tile, BK=32, 4 waves. A is f32, converted to bf16 during staging.
// grid (5, 340).
// ---------------------------------------------------------------------------
__global__ __launch_bounds__(256) void gemm_pre(const float* __restrict__ inpf,
                                                const float* __restrict__ query,
                                                const unsigned short* __restrict__ Wt_val,
                                                const unsigned short* __restrict__ Wt_oa,
                                                const float* __restrict__ b_val,
                                                const float* __restrict__ b_off,
                                                const float* __restrict__ b_attn,
                                                unsigned short* __restrict__ val_h,
                                                unsigned short* __restrict__ oa_h) {
    __shared__ unsigned short As[128 * 32];
    __shared__ unsigned short Bs[128 * 32];
    const int t = threadIdx.x;
    const int wv = t >> 6;
    const int ln = t & 63;
    const int job = (blockIdx.x >= 2);
    const int n0 = (job ? (blockIdx.x - 2) : blockIdx.x) * 128;
    const int m0 = blockIdx.y * 128;
    const float* A = job ? query : inpf;
    const unsigned short* Bt = job ? Wt_oa : Wt_val;
    const int K = 256;
    const int wm = (wv & 1) * 64;
    const int wn = (wv >> 1) * 64;
    const int lrow = ln & 15;
    const int kq = ln >> 4;

    f32x4 acc[4][4] = {};

    for (int k0 = 0; k0 < K; k0 += 32) {
#pragma unroll
        for (int c = 0; c < 4; ++c) {
            const int i = t + c * 256;
            const int row = i >> 3;
            const int kq4 = (i & 7) * 4;
            f32x4 v = *(const f32x4*)&A[(size_t)(m0 + row) * K + k0 + kq4];
            uint2 p = make_uint2(pk2bf(v.x, v.y), pk2bf(v.z, v.w));
            *(uint2*)((char*)As + row * 64 + kq4 * 2) = p;
        }
#pragma unroll
        for (int c = 0; c < 2; ++c) {
            const int o = c * 4096 + t * 16;
            const int row = o >> 6;
            const int ke = (o & 63) >> 1;
            const unsigned short* gb = Bt + (size_t)(n0 + row) * K + k0 + ke;
            __builtin_amdgcn_global_load_lds(
                (const __attribute__((address_space(1))) void*)gb,
                (__attribute__((address_space(3))) void*)((char*)Bs + o), 16, 0, 0);
        }
        __syncthreads();

        bf16x8 af[4], bfr[4];
#pragma unroll
        for (int i = 0; i < 4; ++i) {
            af[i]  = *(const bf16x8*)((char*)As + (wm + i * 16 + lrow) * 64 + kq * 16);
            bfr[i] = *(const bf16x8*)((char*)Bs + (wn + i * 16 + lrow) * 64 + kq * 16);
        }
#pragma unroll
        for (int i = 0; i < 4; ++i)
#pragma unroll
            for (int j = 0; j < 4; ++j)
                acc[i][j] = __builtin_amdgcn_mfma_f32_16x16x32_bf16(af[i], bfr[j], acc[i][j], 0, 0, 0);
        __syncthreads();
    }

    // epilogue: C/D mapping col = lane&15, row = (lane>>4)*4 + reg
    const int b = m0 / LQ_;       // block never straddles batch (21760 % 128 == 0)
#pragma unroll
    for (int j = 0; j < 4; ++j) {
        const int n = n0 + wn + j * 16 + lrow;
        const float bb = job ? ((n < 256) ? b_off[n] : b_attn[n - 256]) : b_val[n];
#pragma unroll
        for (int i = 0; i < 4; ++i) {
            const int mrow = m0 + wm + i * 16 + kq * 4;
#pragma unroll
            for (int r = 0; r < 4; ++r) {
                const float v = acc[i][j][r] + bb;
                const unsigned short hv = (unsigned short)__half_as_ushort(__float2half(v));
                if (job) {
                    oa_h[(size_t)(mrow + r) * 384 + n] = hv;
                } else {
                    const int pix = (mrow + r) - b * LQ_;
                    const int h = n >> 5, c = n & 31;
                    val_h[((size_t)(b * NH + h) * LQ_ + pix) * HD + c] = hv;
                }
            }
        }
    }
}

// ---------------------------------------------------------------------------
// out = sampled(bf16) @ Wt_out + b_out -> f32. grid (2, 340).
// ---------------------------------------------------------------------------
__global__ __launch_bounds__(256) void gemm_out(const unsigned short* __restrict__ Ab,
                                                const unsigned short* __restrict__ Bt,
                                                const float* __restrict__ bias,
                                                float* __restrict__ C) {
    __shared__ unsigned short As[128 * 32];
    __shared__ unsigned short Bs[128 * 32];
    const int t = threadIdx.x;
    const int wv = t >> 6;
    const int ln = t & 63;
    const int n0 = blockIdx.x * 128;
    const int m0 = blockIdx.y * 128;
    const int N = 256, K = 256;
    const int wm = (wv & 1) * 64;
    const int wn = (wv >> 1) * 64;
    const int lrow = ln & 15;
    const int kq = ln >> 4;

    f32x4 acc[4][4] = {};

    for (int k0 = 0; k0 < K; k0 += 32) {
#pragma unroll
        for (int c = 0; c < 2; ++c) {
            const int o = c * 4096 + t * 16;
            const int row = o >> 6;
            const int ke = (o & 63) >> 1;
            const unsigned short* ga = Ab + (size_t)(m0 + row) * K + k0 + ke;
            const unsigned short* gb = Bt + (size_t)(n0 + row) * K + k0 + ke;
            __builtin_amdgcn_global_load_lds(
                (const __attribute__((address_space(1))) void*)ga,
                (__attribute__((address_space(3))) void*)((char*)As + o), 16, 0, 0);
            __builtin_amdgcn_global_load_lds(
                (const __attribute__((address_space(1))) void*)gb,
                (__attribute__((address_space(3))) void*)((char*)Bs + o), 16, 0, 0);
        }
        __syncthreads();

        bf16x8 af[4], bfr[4];
#pragma unroll
        for (int i = 0; i < 4; ++i) {
            af[i]  = *(const bf16x8*)((char*)As + (wm + i * 16 + lrow) * 64 + kq * 16);
            bfr[i] = *(const bf16x8*)((char*)Bs + (wn + i * 16 + lrow) * 64 + kq * 16);
        }
#pragma unroll
        for (int i = 0; i < 4; ++i)
#pragma unroll
            for (int j = 0; j < 4; ++j)
                acc[i][j] = __builtin_amdgcn_mfma_f32_16x16x32_bf16(af[i], bfr[j], acc[i][j], 0, 0, 0);
        __syncthreads();
    }

#pragma unroll
    for (int j = 0; j < 4; ++j) {
        const int n = n0 + wn + j * 16 + lrow;
        const float bb = bias[n];
#pragma unroll
        for (int i = 0; i < 4; ++i) {
            const int mrow = m0 + wm + i * 16 + kq * 4;
#pragma unroll
            for (int r = 0; r < 4; ++r)
                C[(size_t)(mrow + r) * N + n] = acc[i][j][r] + bb;
        }
    }
}

// ---------------------------------------------------------------------------
// Deformable sampling v8 (reverted from v9 regression): head-partitioned,
// ISA-forced 16-deep gather pipeline. At the per-XCD L2 random-line wall
// (~1.4 GB line traffic / 90 us ~= 2 TB/s per XCD).
// v10 change: SPLIT into 2 dispatches (jbase 0 / 5440) so the ~45 us halves
// no longer saturate the top-5 profile table -> gemm_pre/gemm_out become
// visible with counters next round. Head->XCD mapping (j&7) preserved.
// ---------------------------------------------------------------------------
#define QB6 32

#define MSDA_VMWAIT(n) { asm volatile("s_waitcnt vmcnt(" #n ")" ::: "memory"); \
                         __builtin_amdgcn_sched_barrier(0); }

#define MSDA_ISSUE(i) u32x4 va_##i, vc_##i; { \
    const u32x2 xy = *(const u32x2*)&s_pkw[wb ^ ((i) << 2)]; \
    gload16(va_##i, vbase + (size_t)xy[0] * 64); \
    gload16(vc_##i, vbase + (size_t)xy[1] * 64); }

#define MSDA_CONSUME(i) { \
    const u32x2 zw = *(const u32x2*)&s_pkw[(wb ^ ((i) << 2)) + 2]; \
    const __half2 w0 = u2h2(__builtin_amdgcn_perm(zw[0], zw[0], wsel)); \
    const __half2 w1 = u2h2(__builtin_amdgcn_perm(zw[1], zw[1], wsel)); \
    ah0 = __hfma2(w0, u2h2(va_##i[0]), ah0); \
    ah1 = __hfma2(w0, u2h2(va_##i[1]), ah1); \
    ah2 = __hfma2(w0, u2h2(va_##i[2]), ah2); \
    ah3 = __hfma2(w0, u2h2(va_##i[3]), ah3); \
    ah0 = __hfma2(w1, u2h2(vc_##i[0]), ah0); \
    ah1 = __hfma2(w1, u2h2(vc_##i[1]), ah1); \
    ah2 = __hfma2(w1, u2h2(vc_##i[2]), ah2); \
    ah3 = __hfma2(w1, u2h2(vc_##i[3]), ah3); }

#define MSDA_FLUSH() { \
    float2 f0 = __half22float2(ah0); facc0 += f0.x; facc1 += f0.y; ah0 = u2h2(0u); \
    float2 f1 = __half22float2(ah1); facc2 += f1.x; facc3 += f1.y; ah1 = u2h2(0u); \
    float2 f2 = __half22float2(ah2); facc4 += f2.x; facc5 += f2.y; ah2 = u2h2(0u); \
    float2 f3 = __half22float2(ah3); facc6 += f3.x; facc7 += f3.y; ah3 = u2h2(0u); }

__global__ __launch_bounds__(256) void msda_sample8(const unsigned short* __restrict__ value,
                                                    const unsigned short* __restrict__ oa,
                                                    const float* __restrict__ refp,
                                                    unsigned short* __restrict__ samp,
                                                    const int jbase) {
    __shared__ __align__(16) char smem[9216];
    unsigned int* s_pkw = (unsigned int*)smem;            // 8 KB (phase B), aliases below
    float* s_off   = (float*)smem;                        // 32q * 32 f32 = 4 KB
    float* s_logit = (float*)(smem + 4096);               // 32q * 16 f32 = 2 KB
    float* s_aw    = (float*)(smem + 6144);               // 2 KB
    float* s_ref   = (float*)(smem + 8192);               // 1 KB (non-aliased)

    const int t = threadIdx.x;
    const int j = blockIdx.x + jbase;         // 2 x 5440 blocks
    const int h = j & 7;                      // head, pinned per XCD
    const int bqc = j >> 3;                   // 0..1359
    const int b = (bqc >= 680);
    const int q0 = (bqc - b * 680) * QB6;     // batch-local query base
    const int bq0 = b * LQ_ + q0;             // global row base

    // phase 0: stage this head's oa slice (f16 -> f32) + refs, nontemporal.
    {
        const int q = t >> 3, c = t & 7;
        const unsigned short* oab = oa + (size_t)(bq0 + q) * 384;
        u32x2 r0 = __builtin_nontemporal_load((const u32x2*)(oab + h * 32) + c);
        float2 f0 = __half22float2(u2h2(r0.x));
        float2 f1 = __half22float2(u2h2(r0.y));
        f32x4 o0 = {f0.x, f0.y, f1.x, f1.y};
        ((f32x4*)s_off)[q * 8 + c] = o0;
        unsigned int r1 = __builtin_nontemporal_load((const unsigned int*)(oab + 256 + h * 16) + c);
        float2 g0 = __half22float2(u2h2(r1));
        ((float2*)s_logit)[q * 8 + c] = make_float2(g0.x, g0.y);
        s_ref[q * 8 + c] = __builtin_nontemporal_load(refp + (size_t)(bq0 + q) * 8 + c);
    }
    __syncthreads();

    // phase A1: 32 softmaxes (one per query, this head) over 16 logits
    if (t < 32) {
        const float* lg = s_logit + t * 16;
        float m = -1e30f;
#pragma unroll
        for (int i = 0; i < 16; ++i) m = fmaxf(m, lg[i]);
        float e[16], s = 0.f;
#pragma unroll
        for (int i = 0; i < 16; ++i) { e[i] = __expf(lg[i] - m); s += e[i]; }
        const float inv = 1.f / s;
#pragma unroll
        for (int i = 0; i < 16; ++i) s_aw[t * 16 + i] = e[i] * inv;
    }
    __syncthreads();

    // phase A2: 2 samples/thread -> registers. s = q(5b)*16 + lp(4b)
    uint4 ent[2];
    int wrd[2];
    {
        const int Wls[4] = {128, 64, 32, 16};
        const int Hls[4] = {128, 64, 32, 16};
        const int st_[4] = {0, 16384, 20480, 21504};
#pragma unroll
        for (int ii = 0; ii < 2; ++ii) {
            const int s = t * 2 + ii;
            const int q = s >> 4;
            const int lp = s & 15;
            const int l = lp >> 2;
            const int Wl = Wls[l], Hl = Hls[l], base = st_[l];
            const float ix = s_ref[q * 8 + l * 2]     * (float)Wl - 0.5f + s_off[q * 32 + lp * 2];
            const float iy = s_ref[q * 8 + l * 2 + 1] * (float)Hl - 0.5f + s_off[q * 32 + lp * 2 + 1];
            const float fix = floorf(ix), fiy = floorf(iy);
            const int x0 = (int)fix, y0 = (int)fiy;
            const float fx = ix - fix, fy = iy - fiy;
            int sx; float wl, wr;
            if (x0 < 0)            { sx = 0;      wl = (x0 == -1) ? fx : 0.f;        wr = 0.f; }
            else if (x0 >= Wl - 1) { sx = Wl - 2; wl = 0.f; wr = (x0 == Wl - 1) ? (1.f - fx) : 0.f; }
            else                   { sx = x0;     wl = 1.f - fx;                     wr = fx; }
            const float g0 = ((y0 >= 0) & (y0 < Hl)) ? (1.f - fy) : 0.f;
            const float g1 = ((y0 + 1 >= 0) & (y0 + 1 < Hl)) ? fy : 0.f;
            const int cy0 = min(max(y0, 0), Hl - 1);
            const int cy1 = min(max(y0 + 1, 0), Hl - 1);
            const float aw = s_aw[q * 16 + lp];
            ent[ii].x = (unsigned int)(base + cy0 * Wl + sx);
            ent[ii].y = (unsigned int)(base + cy1 * Wl + sx);
            ent[ii].z = pk2h(aw * wl * g0, aw * wr * g0);
            ent[ii].w = pk2h(aw * wl * g1, aw * wr * g1);
            wrd[ii] = q * 64 + ((lp ^ (q & 7)) << 2);
        }
    }
    __syncthreads();  // phase-A reads done; safe to overwrite aliased region

#pragma unroll
    for (int ii = 0; ii < 2; ++ii)
        *(uint4*)&s_pkw[wrd[ii]] = ent[ii];
    __syncthreads();

    // phase B: wave = 8 queries x 8 dg; lane's pixel = sx + (dg>=4), ch = (dg&3)*8..
    const int lane = t & 63;
    const int wv = t >> 6;
    const int ql = lane >> 3;                 // 0..7 within wave
    const int q = wv * 8 + ql;                // block-local query 0..31
    const int dg = lane & 7;
    const char* vbase = (const char*)(value + ((size_t)(b * NH + h) * LQ_) * HD) + dg * 16;
    const unsigned int wsel = (dg < 4) ? 0x01000100u : 0x03020302u;  // v_perm: replicate lo/hi half
    const int wb = q * 64 + (ql << 2);        // swizzled entry base (bits disjoint from lp<<2)

    float facc0 = 0.f, facc1 = 0.f, facc2 = 0.f, facc3 = 0.f;
    float facc4 = 0.f, facc5 = 0.f, facc6 = 0.f, facc7 = 0.f;
    __half2 ah0 = u2h2(0u), ah1 = u2h2(0u), ah2 = u2h2(0u), ah3 = u2h2(0u);

    // --- forced pipeline: 16 loads in flight steady-state ---
    MSDA_ISSUE(0)  MSDA_ISSUE(1)  MSDA_ISSUE(2)  MSDA_ISSUE(3)
    MSDA_ISSUE(4)  MSDA_ISSUE(5)  MSDA_ISSUE(6)  MSDA_ISSUE(7)
    MSDA_VMWAIT(8)                    // lp 0..3 complete; 4..7 outstanding
    MSDA_ISSUE(8)  MSDA_ISSUE(9)  MSDA_ISSUE(10) MSDA_ISSUE(11)
    MSDA_CONSUME(0) MSDA_CONSUME(1) MSDA_CONSUME(2) MSDA_CONSUME(3)
    MSDA_FLUSH()
    MSDA_VMWAIT(8)                    // lp 4..7 complete; 8..11 outstanding
    MSDA_ISSUE(12) MSDA_ISSUE(13) MSDA_ISSUE(14) MSDA_ISSUE(15)
    MSDA_CONSUME(4) MSDA_CONSUME(5) MSDA_CONSUME(6) MSDA_CONSUME(7)
    MSDA_FLUSH()
    MSDA_VMWAIT(8)                    // lp 8..11 complete; 12..15 outstanding
    MSDA_CONSUME(8) MSDA_CONSUME(9) MSDA_CONSUME(10) MSDA_CONSUME(11)
    MSDA_FLUSH()
    MSDA_VMWAIT(0)                    // all done
    MSDA_CONSUME(12) MSDA_CONSUME(13) MSDA_CONSUME(14) MSDA_CONSUME(15)
    MSDA_FLUSH()

    // combine left-pixel (dg<4) and right-pixel (dg>=4) partials
    facc0 += __shfl_xor(facc0, 4);
    facc1 += __shfl_xor(facc1, 4);
    facc2 += __shfl_xor(facc2, 4);
    facc3 += __shfl_xor(facc3, 4);
    facc4 += __shfl_xor(facc4, 4);
    facc5 += __shfl_xor(facc5, 4);
    facc6 += __shfl_xor(facc6, 4);
    facc7 += __shfl_xor(facc7, 4);

    if (dg < 4) {
        u32x4 o;
        o.x = pk2bf(facc0, facc1);
        o.y = pk2bf(facc2, facc3);
        o.z = pk2bf(facc4, facc5);
        o.w = pk2bf(facc6, facc7);
        __builtin_nontemporal_store(o, (u32x4*)(samp + (size_t)(bq0 + q) * 256 + h * HD + dg * 8));
    }
}

extern "C" void kernel_launch(void* const* d_in, const int* in_sizes, int n_in,
                              void* d_out, int out_size, void* d_ws, size_t ws_size,
                              hipStream_t stream) {
    const float* query  = (const float*)d_in[0];
    const float* refp   = (const float*)d_in[1];
    const float* inpf   = (const float*)d_in[2];
    const float* W_off  = (const float*)d_in[3];
    const float* b_off  = (const float*)d_in[4];
    const float* W_attn = (const float*)d_in[5];
    const float* b_attn = (const float*)d_in[6];
    const float* W_val  = (const float*)d_in[7];
    const float* b_val  = (const float*)d_in[8];
    const float* W_out  = (const float*)d_in[9];
    const float* b_out  = (const float*)d_in[10];
    float* out = (float*)d_out;

    char* ws = (char*)d_ws;
    unsigned short* val_h   = (unsigned short*)(ws + WS_VAL);
    unsigned short* samp_bf = (unsigned short*)(ws + WS_SAMP);
    unsigned short* oa_h    = (unsigned short*)(ws + WS_OA);
    unsigned short* wt      = (unsigned short*)(ws + WS_WT);
    unsigned short* Wt_val  = wt;
    unsigned short* Wt_oa   = wt + 65536;
    unsigned short* Wt_out  = wt + 163840;

    const int M = B_ * LQ_;          // 43520
    const int JH = B_ * NH * (LQ_ / QB6) / 2;   // 5440 blocks per half

    wt_cvt_all<<<dim3(16, 16, 4), 256, 0, stream>>>(W_val, W_off, W_attn, W_out, wt);

    // merged value + off/attn GEMMs
    gemm_pre<<<dim3(5, M / 128), 256, 0, stream>>>(
        inpf, query, Wt_val, Wt_oa, b_val, b_off, b_attn, val_h, oa_h);

    // sampling (head-partitioned, forced gather pipeline) -- split in 2 for
    // profile visibility of the GEMM kernels
    msda_sample8<<<dim3(JH), 256, 0, stream>>>(val_h, oa_h, refp, samp_bf, 0);
    msda_sample8<<<dim3(JH), 256, 0, stream>>>(val_h, oa_h, refp, samp_bf, JH);

    // output projection
    gemm_out<<<dim3(2, M / 128), 256, 0, stream>>>(samp_bf, Wt_out, b_out, out);
}

// Round 6
// 276.445 us; speedup vs baseline: 1.2693x; 1.0266x over previous
//
#include <hip/hip_runtime.h>
#include <hip/hip_bf16.h>
#include <hip/hip_fp16.h>
#include <type_traits>

// ---- problem constants ----
#define B_    2
#define LQ_   21760
#define LEN_  21760
#define DM    256
#define NH    8
#define NL    4
#define NP    4
#define HD    32

// workspace layout (bytes)
#define WS_VAL   0u            // f16 value [B][H][21760][32]      22,282,240
#define WS_SAMP  22282240u     // bf16 sampled [B*LQ][256]         22,282,240
#define WS_OA    44564480u     // f16 off|attn [B*LQ][384]         33,423,360
#define WS_WT    77987840u     // bf16 W^T arena: val|oa|out        458,752

typedef __attribute__((ext_vector_type(4))) float f32x4;
typedef __attribute__((ext_vector_type(8))) short bf16x8;
typedef __attribute__((ext_vector_type(4))) unsigned int u32x4;
typedef __attribute__((ext_vector_type(2))) unsigned int u32x2;

__device__ __forceinline__ unsigned short f2bf(float v) {
    __hip_bfloat16 h = __float2bfloat16(v);
    return *reinterpret_cast<unsigned short*>(&h);
}
__device__ __forceinline__ unsigned int pk2bf(float a, float b) {
    return (unsigned int)f2bf(a) | ((unsigned int)f2bf(b) << 16);
}
__device__ __forceinline__ unsigned int pk2h(float a, float b) {
    __half2 h = __floats2half2_rn(a, b);
    union { __half2 h; unsigned int u; } c; c.h = h; return c.u;
}
__device__ __forceinline__ __half2 u2h2(unsigned int u) {
    union { unsigned int u; __half2 h; } c; c.u = u; return c.h;
}

// forced 16-B load: named register quad, cannot be re-rolled by the scheduler
__device__ __forceinline__ void gload16(u32x4& d, const char* p) {
    asm volatile("global_load_dwordx4 %0, %1, off" : "=v"(d) : "v"(p));
}

// 4 raw-f32 dwords -> 2 packed bf16 dwords
__device__ __forceinline__ uint2 cvt4bf(const u32x4& a) {
    union { unsigned u; float f; } x0, x1, x2, x3;
    x0.u = a[0]; x1.u = a[1]; x2.u = a[2]; x3.u = a[3];
    return make_uint2(pk2bf(x0.f, x1.f), pk2bf(x2.f, x3.f));
}

// ---------------------------------------------------------------------------
// All four weight transposes in one dispatch. W[K=256,N] f32 -> Wt[N,256] bf16.
// ---------------------------------------------------------------------------
__global__ __launch_bounds__(256) void wt_cvt_all(const float* __restrict__ Wv,
                                                  const float* __restrict__ Wo,
                                                  const float* __restrict__ Wa,
                                                  const float* __restrict__ Wu,
                                                  unsigned short* __restrict__ wt) {
    const float* Ws[4] = {Wv, Wo, Wa, Wu};
    const int Ns[4] = {256, 256, 128, 256};
    const unsigned int dof[4] = {0u, 65536u, 131072u, 163840u};
    const int m = blockIdx.z;
    const int n0 = blockIdx.x * 16, k0 = blockIdx.y * 16;
    if (n0 >= Ns[m]) return;
    __shared__ float tile[16][17];
    const int tx = threadIdx.x & 15, ty = threadIdx.x >> 4;
    tile[ty][tx] = Ws[m][(size_t)(k0 + ty) * Ns[m] + n0 + tx];
    __syncthreads();
    wt[dof[m] + (size_t)(n0 + ty) * 256 + k0 + tx] = f2bf(tile[tx][ty]);
}

// ---------------------------------------------------------------------------
// Merged pre-GEMMs v2: 2-phase software pipeline (T3/T4), counted vmcnt, raw
// s_barrier, XCD-chunked bijective block swizzle (1700 = 8*212+4).
//  job0 (bx=0..1): value = inpf @ Wt_val + b_val -> f16 PERMUTED [b][h][pix][32]
//  job1 (bx=2..4): oa    = query @ Wt_oa + (b_off|b_attn) -> f16 [bq][384]
// Per K-step: issue A(k+1) via 4x asm global_load_dwordx4 (regs, alternating
// sets) + B(k+1) via global_load_lds into Bs[buf^1]; vmcnt(6) drains only
// A(k)+B(k); cvt+ds_write A(k); barrier; 16 MFMA; barrier. Loads stay in
// flight across the whole compute phase (v8-style, proven to materialize).
// ---------------------------------------------------------------------------
#define GP_ISSUE_A(S) { \
    gload16(a##S##0, pA0); gload16(a##S##1, pA1); \
    gload16(a##S##2, pA2); gload16(a##S##3, pA3); \
    pA0 += 128; pA1 += 128; pA2 += 128; pA3 += 128; }

#define GP_ISSUE_B(DST) { \
    __builtin_amdgcn_global_load_lds( \
        (const __attribute__((address_space(1))) void*)pB0, \
        (__attribute__((address_space(3))) void*)((DST) + o0), 16, 0, 0); \
    __builtin_amdgcn_global_load_lds( \
        (const __attribute__((address_space(1))) void*)pB1, \
        (__attribute__((address_space(3))) void*)((DST) + o1), 16, 0, 0); \
    pB0 += 32; pB1 += 32; }

#define GP_WRITE_A(S) { \
    *(uint2*)as0 = cvt4bf(a##S##0); \
    *(uint2*)as1 = cvt4bf(a##S##1); \
    *(uint2*)as2 = cvt4bf(a##S##2); \
    *(uint2*)as3 = cvt4bf(a##S##3); }

#define GP_COMPUTE(BSRC) { \
    bf16x8 af[4], bfr[4]; \
    _Pragma("unroll") \
    for (int i = 0; i < 4; ++i) { \
        af[i]  = *(const bf16x8*)((const char*)As + (wm + i * 16 + lrow) * 64 + kq * 16); \
        bfr[i] = *(const bf16x8*)((BSRC) + (wn + i * 16 + lrow) * 64 + kq * 16); \
    } \
    _Pragma("unroll") \
    for (int i = 0; i < 4; ++i) \
        _Pragma("unroll") \
        for (int jj = 0; jj < 4; ++jj) \
            acc[i][jj] = __builtin_amdgcn_mfma_f32_16x16x32_bf16(af[i], bfr[jj], acc[i][jj], 0, 0, 0); }

#define GP_STEP(ISS, USE, VM, BCUR, BNXT) { \
    GP_ISSUE_A(ISS) \
    GP_ISSUE_B(BNXT) \
    asm volatile("s_waitcnt vmcnt(" #VM ")" ::: "memory"); \
    __builtin_amdgcn_sched_barrier(0); \
    GP_WRITE_A(USE) \
    asm volatile("s_waitcnt lgkmcnt(0)" ::: "memory"); \
    __builtin_amdgcn_s_barrier(); \
    __builtin_amdgcn_sched_barrier(0); \
    GP_COMPUTE(BCUR) \
    __builtin_amdgcn_s_barrier(); }

__global__ __launch_bounds__(256) void gemm_pre2(const float* __restrict__ inpf,
                                                 const float* __restrict__ query,
                                                 const unsigned short* __restrict__ Wt_val,
                                                 const unsigned short* __restrict__ Wt_oa,
                                                 const float* __restrict__ b_val,
                                                 const float* __restrict__ b_off,
                                                 const float* __restrict__ b_attn,
                                                 unsigned short* __restrict__ val_h,
                                                 unsigned short* __restrict__ oa_h) {
    __shared__ unsigned short As[128 * 32];
    __shared__ unsigned short Bs0[128 * 32];
    __shared__ unsigned short Bs1[128 * 32];
    const int t = threadIdx.x;
    const int wv = t >> 6;
    const int ln = t & 63;

    // bijective XCD-chunk swizzle: consecutive same-XCD blocks share A-tiles
    const int i0 = blockIdx.x;                 // 0..1699
    const int xcd = i0 & 7, off = i0 >> 3;
    const int wg = (xcd < 4 ? xcd * 213 : 852 + (xcd - 4) * 212) + off;
    const int by = wg / 5, bx = wg - by * 5;

    const int job = (bx >= 2);
    const int n0 = (job ? (bx - 2) : bx) * 128;
    const int m0 = by * 128;
    const float* A = job ? query : inpf;
    const unsigned short* Bt = job ? Wt_oa : Wt_val;
    const int wm = (wv & 1) * 64;
    const int wn = (wv >> 1) * 64;
    const int lrow = ln & 15;
    const int kq = ln >> 4;

    // per-thread A staging geometry: i = t + c*256 -> row = (t>>3)+32c, kq4 = (t&7)*4
    const int rA = t >> 3;
    const int kq4 = (t & 7) * 4;
    const char* pA0 = (const char*)(A + (size_t)(m0 + rA) * 256 + kq4);
    const char* pA1 = pA0 + 32 * 256 * 4;
    const char* pA2 = pA1 + 32 * 256 * 4;
    const char* pA3 = pA2 + 32 * 256 * 4;
    char* as0 = (char*)As + rA * 64 + kq4 * 2;
    char* as1 = as0 + 32 * 64;
    char* as2 = as1 + 32 * 64;
    char* as3 = as2 + 32 * 64;

    // per-thread B staging geometry: o = c*4096 + t*16
    const int o0 = t * 16, o1 = 4096 + t * 16;
    const int brow0 = o0 >> 6, ke0 = (o0 & 63) >> 1;
    const int brow1 = o1 >> 6, ke1 = (o1 & 63) >> 1;
    const unsigned short* pB0 = Bt + (size_t)(n0 + brow0) * 256 + ke0;
    const unsigned short* pB1 = Bt + (size_t)(n0 + brow1) * 256 + ke1;
    char* bsc0 = (char*)Bs0;
    char* bsc1 = (char*)Bs1;

    f32x4 acc[4][4] = {};
    u32x4 aA0, aA1, aA2, aA3, aB0, aB1, aB2, aB3;

    // prologue: A(0) -> set A regs, B(0) -> Bs0
    GP_ISSUE_A(A)
    GP_ISSUE_B(bsc0)

    GP_STEP(B, A, 6, bsc0, bsc1)   // k=0
    GP_STEP(A, B, 6, bsc1, bsc0)   // k=1
    GP_STEP(B, A, 6, bsc0, bsc1)   // k=2
    GP_STEP(A, B, 6, bsc1, bsc0)   // k=3
    GP_STEP(B, A, 6, bsc0, bsc1)   // k=4
    GP_STEP(A, B, 6, bsc1, bsc0)   // k=5
    GP_STEP(B, A, 6, bsc0, bsc1)   // k=6
    // k=7: no issue, drain everything
    asm volatile("s_waitcnt vmcnt(0)" ::: "memory");
    __builtin_amdgcn_sched_barrier(0);
    GP_WRITE_A(B)
    asm volatile("s_waitcnt lgkmcnt(0)" ::: "memory");
    __builtin_amdgcn_s_barrier();
    __builtin_amdgcn_sched_barrier(0);
    GP_COMPUTE(bsc1)

    // epilogue: C/D mapping col = lane&15, row = (lane>>4)*4 + reg
    const int b = m0 / LQ_;       // block never straddles batch (21760 % 128 == 0)
#pragma unroll
    for (int j = 0; j < 4; ++j) {
        const int n = n0 + wn + j * 16 + lrow;
        const float bb = job ? ((n < 256) ? b_off[n] : b_attn[n - 256]) : b_val[n];
#pragma unroll
        for (int i = 0; i < 4; ++i) {
            const int mrow = m0 + wm + i * 16 + kq * 4;
#pragma unroll
            for (int r = 0; r < 4; ++r) {
                const float v = acc[i][j][r] + bb;
                const unsigned short hv = (unsigned short)__half_as_ushort(__float2half(v));
                if (job) {
                    oa_h[(size_t)(mrow + r) * 384 + n] = hv;
                } else {
                    const int pix = (mrow + r) - b * LQ_;
                    const int h = n >> 5, c = n & 31;
                    val_h[((size_t)(b * NH + h) * LQ_ + pix) * HD + c] = hv;
                }
            }
        }
    }
}

// ---------------------------------------------------------------------------
// out = sampled(bf16) @ Wt_out + b_out -> f32. grid (2, 340).
// ---------------------------------------------------------------------------
__global__ __launch_bounds__(256) void gemm_out(const unsigned short* __restrict__ Ab,
                                                const unsigned short* __restrict__ Bt,
                                                const float* __restrict__ bias,
                                                float* __restrict__ C) {
    __shared__ unsigned short As[128 * 32];
    __shared__ unsigned short Bs[128 * 32];
    const int t = threadIdx.x;
    const int wv = t >> 6;
    const int ln = t & 63;
    const int n0 = blockIdx.x * 128;
    const int m0 = blockIdx.y * 128;
    const int N = 256, K = 256;
    const int wm = (wv & 1) * 64;
    const int wn = (wv >> 1) * 64;
    const int lrow = ln & 15;
    const int kq = ln >> 4;

    f32x4 acc[4][4] = {};

    for (int k0 = 0; k0 < K; k0 += 32) {
#pragma unroll
        for (int c = 0; c < 2; ++c) {
            const int o = c * 4096 + t * 16;
            const int row = o >> 6;
            const int ke = (o & 63) >> 1;
            const unsigned short* ga = Ab + (size_t)(m0 + row) * K + k0 + ke;
            const unsigned short* gb = Bt + (size_t)(n0 + row) * K + k0 + ke;
            __builtin_amdgcn_global_load_lds(
                (const __attribute__((address_space(1))) void*)ga,
                (__attribute__((address_space(3))) void*)((char*)As + o), 16, 0, 0);
            __builtin_amdgcn_global_load_lds(
                (const __attribute__((address_space(1))) void*)gb,
                (__attribute__((address_space(3))) void*)((char*)Bs + o), 16, 0, 0);
        }
        __syncthreads();

        bf16x8 af[4], bfr[4];
#pragma unroll
        for (int i = 0; i < 4; ++i) {
            af[i]  = *(const bf16x8*)((char*)As + (wm + i * 16 + lrow) * 64 + kq * 16);
            bfr[i] = *(const bf16x8*)((char*)Bs + (wn + i * 16 + lrow) * 64 + kq * 16);
        }
#pragma unroll
        for (int i = 0; i < 4; ++i)
#pragma unroll
            for (int j = 0; j < 4; ++j)
                acc[i][j] = __builtin_amdgcn_mfma_f32_16x16x32_bf16(af[i], bfr[j], acc[i][j], 0, 0, 0);
        __syncthreads();
    }

#pragma unroll
    for (int j = 0; j < 4; ++j) {
        const int n = n0 + wn + j * 16 + lrow;
        const float bb = bias[n];
#pragma unroll
        for (int i = 0; i < 4; ++i) {
            const int mrow = m0 + wm + i * 16 + kq * 4;
#pragma unroll
            for (int r = 0; r < 4; ++r)
                C[(size_t)(mrow + r) * N + n] = acc[i][j][r] + bb;
        }
    }
}

// ---------------------------------------------------------------------------
// Deformable sampling v8: head-partitioned, ISA-forced 16-deep gather
// pipeline. At the per-XCD L2 random-line wall. Split into 2 dispatches for
// profile-table visibility of the GEMM kernels.
// ---------------------------------------------------------------------------
#define QB6 32

#define MSDA_VMWAIT(n) { asm volatile("s_waitcnt vmcnt(" #n ")" ::: "memory"); \
                         __builtin_amdgcn_sched_barrier(0); }

#define MSDA_ISSUE(i) u32x4 va_##i, vc_##i; { \
    const u32x2 xy = *(const u32x2*)&s_pkw[wb ^ ((i) << 2)]; \
    gload16(va_##i, vbase + (size_t)xy[0] * 64); \
    gload16(vc_##i, vbase + (size_t)xy[1] * 64); }

#define MSDA_CONSUME(i) { \
    const u32x2 zw = *(const u32x2*)&s_pkw[(wb ^ ((i) << 2)) + 2]; \
    const __half2 w0 = u2h2(__builtin_amdgcn_perm(zw[0], zw[0], wsel)); \
    const __half2 w1 = u2h2(__builtin_amdgcn_perm(zw[1], zw[1], wsel)); \
    ah0 = __hfma2(w0, u2h2(va_##i[0]), ah0); \
    ah1 = __hfma2(w0, u2h2(va_##i[1]), ah1); \
    ah2 = __hfma2(w0, u2h2(va_##i[2]), ah2); \
    ah3 = __hfma2(w0, u2h2(va_##i[3]), ah3); \
    ah0 = __hfma2(w1, u2h2(vc_##i[0]), ah0); \
    ah1 = __hfma2(w1, u2h2(vc_##i[1]), ah1); \
    ah2 = __hfma2(w1, u2h2(vc_##i[2]), ah2); \
    ah3 = __hfma2(w1, u2h2(vc_##i[3]), ah3); }

#define MSDA_FLUSH() { \
    float2 f0 = __half22float2(ah0); facc0 += f0.x; facc1 += f0.y; ah0 = u2h2(0u); \
    float2 f1 = __half22float2(ah1); facc2 += f1.x; facc3 += f1.y; ah1 = u2h2(0u); \
    float2 f2 = __half22float2(ah2); facc4 += f2.x; facc5 += f2.y; ah2 = u2h2(0u); \
    float2 f3 = __half22float2(ah3); facc6 += f3.x; facc7 += f3.y; ah3 = u2h2(0u); }

__global__ __launch_bounds__(256) void msda_sample8(const unsigned short* __restrict__ value,
                                                    const unsigned short* __restrict__ oa,
                                                    const float* __restrict__ refp,
                                                    unsigned short* __restrict__ samp,
                                                    const int jbase) {
    __shared__ __align__(16) char smem[9216];
    unsigned int* s_pkw = (unsigned int*)smem;            // 8 KB (phase B), aliases below
    float* s_off   = (float*)smem;                        // 32q * 32 f32 = 4 KB
    float* s_logit = (float*)(smem + 4096);               // 32q * 16 f32 = 2 KB
    float* s_aw    = (float*)(smem + 6144);               // 2 KB
    float* s_ref   = (float*)(smem + 8192);               // 1 KB (non-aliased)

    const int t = threadIdx.x;
    const int j = blockIdx.x + jbase;         // 2 x 5440 blocks
    const int h = j & 7;                      // head, pinned per XCD
    const int bqc = j >> 3;                   // 0..1359
    const int b = (bqc >= 680);
    const int q0 = (bqc - b * 680) * QB6;     // batch-local query base
    const int bq0 = b * LQ_ + q0;             // global row base

    // phase 0: stage this head's oa slice (f16 -> f32) + refs, nontemporal.
    {
        const int q = t >> 3, c = t & 7;
        const unsigned short* oab = oa + (size_t)(bq0 + q) * 384;
        u32x2 r0 = __builtin_nontemporal_load((const u32x2*)(oab + h * 32) + c);
        float2 f0 = __half22float2(u2h2(r0.x));
        float2 f1 = __half22float2(u2h2(r0.y));
        f32x4 o0 = {f0.x, f0.y, f1.x, f1.y};
        ((f32x4*)s_off)[q * 8 + c] = o0;
        unsigned int r1 = __builtin_nontemporal_load((const unsigned int*)(oab + 256 + h * 16) + c);
        float2 g0 = __half22float2(u2h2(r1));
        ((float2*)s_logit)[q * 8 + c] = make_float2(g0.x, g0.y);
        s_ref[q * 8 + c] = __builtin_nontemporal_load(refp + (size_t)(bq0 + q) * 8 + c);
    }
    __syncthreads();

    // phase A1: 32 softmaxes (one per query, this head) over 16 logits
    if (t < 32) {
        const float* lg = s_logit + t * 16;
        float m = -1e30f;
#pragma unroll
        for (int i = 0; i < 16; ++i) m = fmaxf(m, lg[i]);
        float e[16], s = 0.f;
#pragma unroll
        for (int i = 0; i < 16; ++i) { e[i] = __expf(lg[i] - m); s += e[i]; }
        const float inv = 1.f / s;
#pragma unroll
        for (int i = 0; i < 16; ++i) s_aw[t * 16 + i] = e[i] * inv;
    }
    __syncthreads();

    // phase A2: 2 samples/thread -> registers. s = q(5b)*16 + lp(4b)
    uint4 ent[2];
    int wrd[2];
    {
        const int Wls[4] = {128, 64, 32, 16};
        const int Hls[4] = {128, 64, 32, 16};
        const int st_[4] = {0, 16384, 20480, 21504};
#pragma unroll
        for (int ii = 0; ii < 2; ++ii) {
            const int s = t * 2 + ii;
            const int q = s >> 4;
            const int lp = s & 15;
            const int l = lp >> 2;
            const int Wl = Wls[l], Hl = Hls[l], base = st_[l];
            const float ix = s_ref[q * 8 + l * 2]     * (float)Wl - 0.5f + s_off[q * 32 + lp * 2];
            const float iy = s_ref[q * 8 + l * 2 + 1] * (float)Hl - 0.5f + s_off[q * 32 + lp * 2 + 1];
            const float fix = floorf(ix), fiy = floorf(iy);
            const int x0 = (int)fix, y0 = (int)fiy;
            const float fx = ix - fix, fy = iy - fiy;
            int sx; float wl, wr;
            if (x0 < 0)            { sx = 0;      wl = (x0 == -1) ? fx : 0.f;        wr = 0.f; }
            else if (x0 >= Wl - 1) { sx = Wl - 2; wl = 0.f; wr = (x0 == Wl - 1) ? (1.f - fx) : 0.f; }
            else                   { sx = x0;     wl = 1.f - fx;                     wr = fx; }
            const float g0 = ((y0 >= 0) & (y0 < Hl)) ? (1.f - fy) : 0.f;
            const float g1 = ((y0 + 1 >= 0) & (y0 + 1 < Hl)) ? fy : 0.f;
            const int cy0 = min(max(y0, 0), Hl - 1);
            const int cy1 = min(max(y0 + 1, 0), Hl - 1);
            const float aw = s_aw[q * 16 + lp];
            ent[ii].x = (unsigned int)(base + cy0 * Wl + sx);
            ent[ii].y = (unsigned int)(base + cy1 * Wl + sx);
            ent[ii].z = pk2h(aw * wl * g0, aw * wr * g0);
            ent[ii].w = pk2h(aw * wl * g1, aw * wr * g1);
            wrd[ii] = q * 64 + ((lp ^ (q & 7)) << 2);
        }
    }
    __syncthreads();  // phase-A reads done; safe to overwrite aliased region

#pragma unroll
    for (int ii = 0; ii < 2; ++ii)
        *(uint4*)&s_pkw[wrd[ii]] = ent[ii];
    __syncthreads();

    // phase B: wave = 8 queries x 8 dg; lane's pixel = sx + (dg>=4), ch = (dg&3)*8..
    const int lane = t & 63;
    const int wv = t >> 6;
    const int ql = lane >> 3;                 // 0..7 within wave
    const int q = wv * 8 + ql;                // block-local query 0..31
    const int dg = lane & 7;
    const char* vbase = (const char*)(value + ((size_t)(b * NH + h) * LQ_) * HD) + dg * 16;
    const unsigned int wsel = (dg < 4) ? 0x01000100u : 0x03020302u;  // v_perm: replicate lo/hi half
    const int wb = q * 64 + (ql << 2);        // swizzled entry base (bits disjoint from lp<<2)

    float facc0 = 0.f, facc1 = 0.f, facc2 = 0.f, facc3 = 0.f;
    float facc4 = 0.f, facc5 = 0.f, facc6 = 0.f, facc7 = 0.f;
    __half2 ah0 = u2h2(0u), ah1 = u2h2(0u), ah2 = u2h2(0u), ah3 = u2h2(0u);

    // --- forced pipeline: 16 loads in flight steady-state ---
    MSDA_ISSUE(0)  MSDA_ISSUE(1)  MSDA_ISSUE(2)  MSDA_ISSUE(3)
    MSDA_ISSUE(4)  MSDA_ISSUE(5)  MSDA_ISSUE(6)  MSDA_ISSUE(7)
    MSDA_VMWAIT(8)                    // lp 0..3 complete; 4..7 outstanding
    MSDA_ISSUE(8)  MSDA_ISSUE(9)  MSDA_ISSUE(10) MSDA_ISSUE(11)
    MSDA_CONSUME(0) MSDA_CONSUME(1) MSDA_CONSUME(2) MSDA_CONSUME(3)
    MSDA_FLUSH()
    MSDA_VMWAIT(8)                    // lp 4..7 complete; 8..11 outstanding
    MSDA_ISSUE(12) MSDA_ISSUE(13) MSDA_ISSUE(14) MSDA_ISSUE(15)
    MSDA_CONSUME(4) MSDA_CONSUME(5) MSDA_CONSUME(6) MSDA_CONSUME(7)
    MSDA_FLUSH()
    MSDA_VMWAIT(8)                    // lp 8..11 complete; 12..15 outstanding
    MSDA_CONSUME(8) MSDA_CONSUME(9) MSDA_CONSUME(10) MSDA_CONSUME(11)
    MSDA_FLUSH()
    MSDA_VMWAIT(0)                    // all done
    MSDA_CONSUME(12) MSDA_CONSUME(13) MSDA_CONSUME(14) MSDA_CONSUME(15)
    MSDA_FLUSH()

    // combine left-pixel (dg<4) and right-pixel (dg>=4) partials
    facc0 += __shfl_xor(facc0, 4);
    facc1 += __shfl_xor(facc1, 4);
    facc2 += __shfl_xor(facc2, 4);
    facc3 += __shfl_xor(facc3, 4);
    facc4 += __shfl_xor(facc4, 4);
    facc5 += __shfl_xor(facc5, 4);
    facc6 += __shfl_xor(facc6, 4);
    facc7 += __shfl_xor(facc7, 4);

    if (dg < 4) {
        u32x4 o;
        o.x = pk2bf(facc0, facc1);
        o.y = pk2bf(facc2, facc3);
        o.z = pk2bf(facc4, facc5);
        o.w = pk2bf(facc6, facc7);
        __builtin_nontemporal_store(o, (u32x4*)(samp + (size_t)(bq0 + q) * 256 + h * HD + dg * 8));
    }
}

extern "C" void kernel_launch(void* const* d_in, const int* in_sizes, int n_in,
                              void* d_out, int out_size, void* d_ws, size_t ws_size,
                              hipStream_t stream) {
    const float* query  = (const float*)d_in[0];
    const float* refp   = (const float*)d_in[1];
    const float* inpf   = (const float*)d_in[2];
    const float* W_off  = (const float*)d_in[3];
    const float* b_off  = (const float*)d_in[4];
    const float* W_attn = (const float*)d_in[5];
    const float* b_attn = (const float*)d_in[6];
    const float* W_val  = (const float*)d_in[7];
    const float* b_val  = (const float*)d_in[8];
    const float* W_out  = (const float*)d_in[9];
    const float* b_out  = (const float*)d_in[10];
    float* out = (float*)d_out;

    char* ws = (char*)d_ws;
    unsigned short* val_h   = (unsigned short*)(ws + WS_VAL);
    unsigned short* samp_bf = (unsigned short*)(ws + WS_SAMP);
    unsigned short* oa_h    = (unsigned short*)(ws + WS_OA);
    unsigned short* wt      = (unsigned short*)(ws + WS_WT);
    unsigned short* Wt_val  = wt;
    unsigned short* Wt_oa   = wt + 65536;
    unsigned short* Wt_out  = wt + 163840;

    const int M = B_ * LQ_;          // 43520
    const int JH = B_ * NH * (LQ_ / QB6) / 2;   // 5440 blocks per half

    wt_cvt_all<<<dim3(16, 16, 4), 256, 0, stream>>>(W_val, W_off, W_attn, W_out, wt);

    // merged value + off/attn GEMMs (2-phase pipelined, XCD-swizzled)
    gemm_pre2<<<dim3(5 * (M / 128)), 256, 0, stream>>>(
        inpf, query, Wt_val, Wt_oa, b_val, b_off, b_attn, val_h, oa_h);

    // sampling (head-partitioned, forced gather pipeline), split in 2
    msda_sample8<<<dim3(JH), 256, 0, stream>>>(val_h, oa_h, refp, samp_bf, 0);
    msda_sample8<<<dim3(JH), 256, 0, stream>>>(val_h, oa_h, refp, samp_bf, JH);

    // output projection
    gemm_out<<<dim3(2, M / 128), 256, 0, stream>>>(samp_bf, Wt_out, b_out, out);
}